// Round 1
// baseline (382.171 us; speedup 1.0000x reference)
//
#include <hip/hip_runtime.h>

// Problem constants (match reference)
constexpr int Bn   = 4096;
constexpr int Nn   = 32;
constexpr int OBSn = 128;
constexpr int Hn   = 64;
constexpr int An   = 16;

__device__ __forceinline__ float fsig(float x)  { return 1.0f / (1.0f + __expf(-x)); }
__device__ __forceinline__ float ftanh(float x) { return 1.0f - 2.0f / (__expf(2.0f * x) + 1.0f); }

// One block per batch element b. 256 threads = 4 waves.
// Thread map for H-wide ops: hh = t & 63 (column), rg = t >> 6 (wave id, row group),
// each thread owns rows rg*8 .. rg*8+7 at column hh.
// Within a wave rg is uniform -> all A-operand LDS reads are broadcasts.
__global__ __launch_bounds__(256, 3) void commnet_fwd(
    const float* __restrict__ obs,
    const float* __restrict__ enc_W, const float* __restrict__ enc_b,
    const float* __restrict__ msg_W0, const float* __restrict__ msg_b0,
    const float* __restrict__ msg_W1, const float* __restrict__ msg_b1,
    const float* __restrict__ lstm_Wx0, const float* __restrict__ lstm_Wh0, const float* __restrict__ lstm_b0,
    const float* __restrict__ lstm_Wx1, const float* __restrict__ lstm_Wh1, const float* __restrict__ lstm_b1,
    const float* __restrict__ act_W, const float* __restrict__ act_b,
    const float* __restrict__ val_W, const float* __restrict__ val_b,
    float* __restrict__ out)
{
    __shared__ __align__(16) float s_x[Nn * Hn];      // encoded obs (tanh)
    __shared__ __align__(16) float s_h[Nn * Hn];      // h state
    __shared__ __align__(16) float s_c[Nn * Hn];      // c state
    __shared__ __align__(16) float s_buf[Nn * OBSn];  // obs staging; later [comm | z]
    __shared__ __align__(16) float s_red[4 * Hn];     // column-sum reduction

    const int b  = blockIdx.x;
    const int t  = threadIdx.x;
    const int hh = t & (Hn - 1);
    const int rg = t >> 6;      // 0..3, uniform within a wave
    const int r0 = rg * 8;

    // ---- stage obs[b] (32x128 f32 = 16 KB), coalesced float4 ----
    const float* obsb = obs + (size_t)b * (Nn * OBSn);
    for (int i = t; i < Nn * OBSn / 4; i += 256)
        ((float4*)s_buf)[i] = ((const float4*)obsb)[i];
    __syncthreads();

    // ---- encoder: x = tanh(obs @ enc_W + enc_b) ----
    {
        float acc[8];
        #pragma unroll
        for (int r = 0; r < 8; ++r) acc[r] = 0.0f;
        for (int k = 0; k < OBSn; ++k) {
            float w = enc_W[k * Hn + hh];           // coalesced, L1-resident
            #pragma unroll
            for (int r = 0; r < 8; ++r)
                acc[r] = fmaf(s_buf[(r0 + r) * OBSn + k], w, acc[r]);  // LDS broadcast
        }
        float bb = enc_b[hh];
        #pragma unroll
        for (int r = 0; r < 8; ++r) {
            s_x[(r0 + r) * Hn + hh] = ftanh(acc[r] + bb);
            s_h[(r0 + r) * Hn + hh] = 0.0f;
            s_c[(r0 + r) * Hn + hh] = 0.0f;
        }
    }
    __syncthreads();

    float* s_comm = s_buf;            // 32x64
    float* s_z    = s_buf + Nn * Hn;  // 32x64
    const float inv_den = 1.0f / 31.0f;

    #pragma unroll 1
    for (int hop = 0; hop < 2; ++hop) {
        const float* mW = hop ? msg_W1   : msg_W0;
        const float* mb = hop ? msg_b1   : msg_b0;
        const float* Wx = hop ? lstm_Wx1 : lstm_Wx0;
        const float* Wh = hop ? lstm_Wh1 : lstm_Wh0;
        const float* lb = hop ? lstm_b1  : lstm_b0;

        // ---- comm[i] = (sum_j h[j] - h[i]) / 31 ----
        float part = 0.0f;
        #pragma unroll
        for (int r = 0; r < 8; ++r) part += s_h[(r0 + r) * Hn + hh];
        s_red[rg * Hn + hh] = part;
        __syncthreads();
        float S = s_red[0 * Hn + hh] + s_red[1 * Hn + hh]
                + s_red[2 * Hn + hh] + s_red[3 * Hn + hh];
        #pragma unroll
        for (int r = 0; r < 8; ++r)
            s_comm[(r0 + r) * Hn + hh] = (S - s_h[(r0 + r) * Hn + hh]) * inv_den;
        __syncthreads();

        // ---- msg = comm @ mW + mb ; z = x + msg ----
        {
            float acc[8];
            #pragma unroll
            for (int r = 0; r < 8; ++r) acc[r] = 0.0f;
            for (int k = 0; k < Hn; ++k) {
                float w = mW[k * Hn + hh];
                #pragma unroll
                for (int r = 0; r < 8; ++r)
                    acc[r] = fmaf(s_comm[(r0 + r) * Hn + k], w, acc[r]);
            }
            float mbv = mb[hh];
            #pragma unroll
            for (int r = 0; r < 8; ++r)
                s_z[(r0 + r) * Hn + hh] = s_x[(r0 + r) * Hn + hh] + acc[r] + mbv;
        }
        __syncthreads();

        // ---- gates = z @ Wx + h @ Wh + lb (i,f,g,o) ----
        float acc[4][8];
        #pragma unroll
        for (int g = 0; g < 4; ++g)
            #pragma unroll
            for (int r = 0; r < 8; ++r) acc[g][r] = 0.0f;

        for (int k = 0; k < Hn; ++k) {
            float wx[4], wh[4];
            #pragma unroll
            for (int g = 0; g < 4; ++g) {
                wx[g] = Wx[k * 256 + g * Hn + hh];
                wh[g] = Wh[k * 256 + g * Hn + hh];
            }
            #pragma unroll
            for (int r = 0; r < 8; ++r) {
                float zv = s_z[(r0 + r) * Hn + k];
                float hv = s_h[(r0 + r) * Hn + k];
                #pragma unroll
                for (int g = 0; g < 4; ++g)
                    acc[g][r] = fmaf(zv, wx[g], fmaf(hv, wh[g], acc[g][r]));
            }
        }

        float bi = lb[0 * Hn + hh], bf = lb[1 * Hn + hh];
        float bg = lb[2 * Hn + hh], bo = lb[3 * Hn + hh];

        __syncthreads();   // all reads of s_h / s_z in matmul done before overwrite

        #pragma unroll
        for (int r = 0; r < 8; ++r) {
            int row = r0 + r;
            float i_ = fsig (acc[0][r] + bi);
            float f_ = fsig (acc[1][r] + bf);
            float g_ = ftanh(acc[2][r] + bg);
            float o_ = fsig (acc[3][r] + bo);
            float cn = fmaf(f_, s_c[row * Hn + hh], i_ * g_);
            float hn = o_ * ftanh(cn);
            float hr = ftanh(hn + s_z[row * Hn + hh]);
            s_h[row * Hn + hh] = hr;
            s_c[row * Hn + hh] = cn;
        }
        __syncthreads();
    }

    // ---- heads ----
    // logits (B,N,16): thread t -> a = t&15, rows (t>>4) and (t>>4)+16
    {
        const int a  = t & (An - 1);
        const int rr = t >> 4;  // 0..15
        float acc0 = 0.0f, acc1 = 0.0f;
        for (int k = 0; k < Hn; ++k) {
            float w = act_W[k * An + a];
            acc0 = fmaf(s_h[rr * Hn + k],        w, acc0);
            acc1 = fmaf(s_h[(rr + 16) * Hn + k], w, acc1);
        }
        float ab = act_b[a];
        float* lo = out + (size_t)(b * Nn) * An;
        lo[rr * An + a]        = acc0 + ab;
        lo[(rr + 16) * An + a] = acc1 + ab;
    }

    // values (B,N): 8 threads per row, shuffle-reduce
    {
        const int r = t >> 3;   // 0..31
        const int j = t & 7;
        float acc = 0.0f;
        #pragma unroll
        for (int kk = 0; kk < 8; ++kk)
            acc = fmaf(s_h[r * Hn + j * 8 + kk], val_W[j * 8 + kk], acc);
        acc += __shfl_xor(acc, 1);
        acc += __shfl_xor(acc, 2);
        acc += __shfl_xor(acc, 4);
        if (j == 0)
            out[(size_t)Bn * Nn * An + (size_t)b * Nn + r] = acc + val_b[0];
    }

    // h_round, c_round (B,N,64)
    {
        float* oh = out + (size_t)Bn * Nn * (An + 1);
        float* oc = oh + (size_t)Bn * Nn * Hn;
        #pragma unroll
        for (int r = 0; r < 8; ++r) {
            int row = r0 + r;
            oh[((size_t)b * Nn + row) * Hn + hh] = s_h[row * Hn + hh];
            oc[((size_t)b * Nn + row) * Hn + hh] = s_c[row * Hn + hh];
        }
    }
}

extern "C" void kernel_launch(void* const* d_in, const int* in_sizes, int n_in,
                              void* d_out, int out_size, void* d_ws, size_t ws_size,
                              hipStream_t stream) {
    const float* obs      = (const float*)d_in[0];
    const float* enc_W    = (const float*)d_in[1];
    const float* enc_b    = (const float*)d_in[2];
    const float* msg_W0   = (const float*)d_in[3];
    const float* msg_b0   = (const float*)d_in[4];
    const float* msg_W1   = (const float*)d_in[5];
    const float* msg_b1   = (const float*)d_in[6];
    const float* lstm_Wx0 = (const float*)d_in[7];
    const float* lstm_Wh0 = (const float*)d_in[8];
    const float* lstm_b0  = (const float*)d_in[9];
    const float* lstm_Wx1 = (const float*)d_in[10];
    const float* lstm_Wh1 = (const float*)d_in[11];
    const float* lstm_b1  = (const float*)d_in[12];
    const float* act_W    = (const float*)d_in[13];
    const float* act_b    = (const float*)d_in[14];
    const float* val_W    = (const float*)d_in[15];
    const float* val_b    = (const float*)d_in[16];

    commnet_fwd<<<Bn, 256, 0, stream>>>(
        obs, enc_W, enc_b, msg_W0, msg_b0, msg_W1, msg_b1,
        lstm_Wx0, lstm_Wh0, lstm_b0, lstm_Wx1, lstm_Wh1, lstm_b1,
        act_W, act_b, val_W, val_b, (float*)d_out);
}

// Round 2
// 60.172 us; speedup vs baseline: 6.3513x; 6.3513x over previous
//
#include <hip/hip_runtime.h>
#include <hip/hip_bf16.h>

// ---------------- problem constants ----------------
constexpr int Bn   = 4096;
constexpr int Nn   = 32;
constexpr int OBSn = 128;
constexpr int Hn   = 64;
constexpr int An   = 16;

// output offsets (floats)
constexpr size_t VOFF = (size_t)Bn * Nn * An;            // 2097152
constexpr size_t HOFF = VOFF + (size_t)Bn * Nn;          // 2228224
constexpr size_t COFF = HOFF + (size_t)Bn * Nn * Hn;     // 10616832

// packed-weight tile bases (tile = 64 lanes x 16B = 1KB)
constexpr int T_ENC  = 0;    // 16 tiles (nt*4+kt), K=128 N=64
constexpr int T_MSG0 = 16;   // 8 tiles (nt*2+kt),  K=64  N=64
constexpr int T_MSG1 = 24;   // 8
constexpr int T_WX0  = 32;   // 32 tiles (ntg*2+kt), K=64 N=256
constexpr int T_WH0  = 64;
constexpr int T_WX1  = 96;
constexpr int T_WH1  = 128;
constexpr int T_ACT  = 160;  // 2 tiles (kt), K=64 N=16
constexpr int T_TOT  = 162;

typedef short bf16x8 __attribute__((ext_vector_type(8)));
typedef float f32x4  __attribute__((ext_vector_type(4)));

union FragU { uint u[4]; uint4 q; bf16x8 v; };

__device__ __forceinline__ uint pkbf(float a, float b) {
    __hip_bfloat16 ha = __float2bfloat16(a);
    __hip_bfloat16 hb = __float2bfloat16(b);
    unsigned short ua, ub;
    __builtin_memcpy(&ua, &ha, 2);
    __builtin_memcpy(&ub, &hb, 2);
    return (uint)ua | ((uint)ub << 16);
}

__device__ __forceinline__ float rcp_(float x) {
#if __has_builtin(__builtin_amdgcn_rcpf)
    return __builtin_amdgcn_rcpf(x);
#else
    return 1.0f / x;
#endif
}
__device__ __forceinline__ float exp2_(float x) {
#if __has_builtin(__builtin_amdgcn_exp2f)
    return __builtin_amdgcn_exp2f(x);
#else
    return exp2f(x);
#endif
}
__device__ __forceinline__ float fsig(float x)  { return rcp_(1.0f + exp2_(-1.44269504f * x)); }
__device__ __forceinline__ float ftanh(float x) { return 1.0f - 2.0f * rcp_(1.0f + exp2_(2.88539008f * x)); }

// ---------------- prep: pack weights to bf16 fragment-linear ----------------
__global__ void commnet_prep(
    const float* __restrict__ encW, const float* __restrict__ m0,
    const float* __restrict__ m1,   const float* __restrict__ wx0,
    const float* __restrict__ wh0,  const float* __restrict__ wx1,
    const float* __restrict__ wh1,  const float* __restrict__ aw,
    uint4* __restrict__ ws)
{
    int gid = blockIdx.x * 256 + threadIdx.x;
    if (gid >= T_TOT * 64) return;
    int tile = gid >> 6, lane = gid & 63;

    const float* W; int N, nt, kt, lt;
    if      (tile < T_MSG0) { W = encW; N = 64;  lt = tile;        nt = lt >> 2; kt = lt & 3; }
    else if (tile < T_MSG1) { W = m0;   N = 64;  lt = tile - T_MSG0; nt = lt >> 1; kt = lt & 1; }
    else if (tile < T_WX0 ) { W = m1;   N = 64;  lt = tile - T_MSG1; nt = lt >> 1; kt = lt & 1; }
    else if (tile < T_WH0 ) { W = wx0;  N = 256; lt = tile - T_WX0;  nt = lt >> 1; kt = lt & 1; }
    else if (tile < T_WX1 ) { W = wh0;  N = 256; lt = tile - T_WH0;  nt = lt >> 1; kt = lt & 1; }
    else if (tile < T_WH1 ) { W = wx1;  N = 256; lt = tile - T_WX1;  nt = lt >> 1; kt = lt & 1; }
    else if (tile < T_ACT ) { W = wh1;  N = 256; lt = tile - T_WH1;  nt = lt >> 1; kt = lt & 1; }
    else                    { W = aw;   N = 16;  lt = tile - T_ACT;  nt = 0;       kt = lt;     }

    int col = nt * 16 + (lane & 15);
    int kb  = kt * 32 + (lane >> 4) * 4;
    uint4 d;
    {
        int k0 = kb;
        d.x = pkbf(W[(k0 + 0) * N + col], W[(k0 + 1) * N + col]);
        d.y = pkbf(W[(k0 + 2) * N + col], W[(k0 + 3) * N + col]);
        k0 = kb + 16;
        d.z = pkbf(W[(k0 + 0) * N + col], W[(k0 + 1) * N + col]);
        d.w = pkbf(W[(k0 + 2) * N + col], W[(k0 + 3) * N + col]);
    }
    ws[(size_t)tile * 64 + lane] = d;
}

// ---------------- main kernel helpers ----------------
__device__ __forceinline__ int sidx(int row, int col) {
    return row * 64 + (col ^ ((row & 7) << 2));   // f32 XOR swizzle, 16B-block preserving
}

__device__ __forceinline__ void write_cd(float* sb, const float v[2][4][4], int lane) {
    const int m = lane & 15, g = lane >> 4;
    #pragma unroll
    for (int rt = 0; rt < 2; ++rt)
        #pragma unroll
        for (int nt = 0; nt < 4; ++nt)
            #pragma unroll
            for (int r = 0; r < 4; ++r)
                sb[sidx(rt * 16 + g * 4 + r, nt * 16 + m)] = v[rt][nt][r];
}

__device__ __forceinline__ void read_af(const float* sb, int lane, FragU af[2][2]) {
    const int m = lane & 15, g = lane >> 4;
    #pragma unroll
    for (int rt = 0; rt < 2; ++rt)
        #pragma unroll
        for (int kt = 0; kt < 2; ++kt)
            #pragma unroll
            for (int h = 0; h < 2; ++h) {
                const float4 x = *(const float4*)&sb[sidx(rt * 16 + m, kt * 32 + h * 16 + g * 4)];
                af[rt][kt].u[2 * h]     = pkbf(x.x, x.y);
                af[rt][kt].u[2 * h + 1] = pkbf(x.z, x.w);
            }
}

template<bool WITHH>
__device__ __forceinline__ void gate_mm(const uint4* __restrict__ wsQ, int wxBase, int whBase,
                                        int gate, const FragU az[2][2], const FragU ah[2][2],
                                        const float* __restrict__ lb, int lane,
                                        float outv[2][4][4])
{
    const int m = lane & 15;
    #pragma unroll
    for (int nt = 0; nt < 4; ++nt) {
        f32x4 a0 = {0.f, 0.f, 0.f, 0.f};
        f32x4 a1 = {0.f, 0.f, 0.f, 0.f};
        const int ntg = gate * 4 + nt;
        #pragma unroll
        for (int kt = 0; kt < 2; ++kt) {
            FragU bw; bw.q = wsQ[(size_t)(wxBase + ntg * 2 + kt) * 64 + lane];
            a0 = __builtin_amdgcn_mfma_f32_16x16x32_bf16(az[0][kt].v, bw.v, a0, 0, 0, 0);
            a1 = __builtin_amdgcn_mfma_f32_16x16x32_bf16(az[1][kt].v, bw.v, a1, 0, 0, 0);
        }
        if (WITHH) {
            #pragma unroll
            for (int kt = 0; kt < 2; ++kt) {
                FragU bw; bw.q = wsQ[(size_t)(whBase + ntg * 2 + kt) * 64 + lane];
                a0 = __builtin_amdgcn_mfma_f32_16x16x32_bf16(ah[0][kt].v, bw.v, a0, 0, 0, 0);
                a1 = __builtin_amdgcn_mfma_f32_16x16x32_bf16(ah[1][kt].v, bw.v, a1, 0, 0, 0);
            }
        }
        const float lbv = lb[gate * 64 + nt * 16 + m];
        #pragma unroll
        for (int r = 0; r < 4; ++r) {
            outv[0][nt][r] = a0[r] + lbv;
            outv[1][nt][r] = a1[r] + lbv;
        }
    }
}

#define FORALL \
    _Pragma("unroll") for (int rt = 0; rt < 2; ++rt) \
    _Pragma("unroll") for (int nt = 0; nt < 4; ++nt) \
    _Pragma("unroll") for (int r = 0; r < 4; ++r)

// ---------------- main kernel: 1 block = 4 batches, 1 wave = 1 batch ----------------
__global__ __launch_bounds__(256, 2) void commnet_main(
    const float* __restrict__ obs, const uint4* __restrict__ wsQ,
    const float* __restrict__ enc_b,
    const float* __restrict__ msg_b0, const float* __restrict__ msg_b1,
    const float* __restrict__ lstm_b0, const float* __restrict__ lstm_b1,
    const float* __restrict__ act_b,
    const float* __restrict__ val_W, const float* __restrict__ val_b,
    float* __restrict__ out)
{
    __shared__ __align__(16) float sball[4 * 2048];   // 8KB per wave, wave-private
    const int t = threadIdx.x;
    const int wid = t >> 6, lane = t & 63;
    const int m = lane & 15, g = lane >> 4;
    float* sb = sball + wid * 2048;
    const int b = blockIdx.x * 4 + wid;

    // ---- encoder: x = tanh(obs @ enc_W + enc_b) ----
    FragU aob[2][4];
    const float* ob = obs + (size_t)b * (Nn * OBSn);
    #pragma unroll
    for (int rt = 0; rt < 2; ++rt)
        #pragma unroll
        for (int kt = 0; kt < 4; ++kt)
            #pragma unroll
            for (int h = 0; h < 2; ++h) {
                const float4 vv = *(const float4*)&ob[(rt * 16 + m) * OBSn + kt * 32 + h * 16 + g * 4];
                aob[rt][kt].u[2 * h]     = pkbf(vv.x, vv.y);
                aob[rt][kt].u[2 * h + 1] = pkbf(vv.z, vv.w);
            }
    float xv[2][4][4];
    #pragma unroll
    for (int nt = 0; nt < 4; ++nt) {
        f32x4 a0 = {0.f, 0.f, 0.f, 0.f};
        f32x4 a1 = {0.f, 0.f, 0.f, 0.f};
        #pragma unroll
        for (int kt = 0; kt < 4; ++kt) {
            FragU bw; bw.q = wsQ[(size_t)(T_ENC + nt * 4 + kt) * 64 + lane];
            a0 = __builtin_amdgcn_mfma_f32_16x16x32_bf16(aob[0][kt].v, bw.v, a0, 0, 0, 0);
            a1 = __builtin_amdgcn_mfma_f32_16x16x32_bf16(aob[1][kt].v, bw.v, a1, 0, 0, 0);
        }
        const float eb = enc_b[nt * 16 + m];
        #pragma unroll
        for (int r = 0; r < 4; ++r) {
            xv[0][nt][r] = ftanh(a0[r] + eb);
            xv[1][nt][r] = ftanh(a1[r] + eb);
        }
    }

    float zv[2][4][4], cv[2][4][4], hv[2][4][4], tg[2][4][4], si[2][4][4];
    FragU az[2][2], ah[2][2];

    // ================= hop 0 (h = c = 0: msg = bias, f-gate moot, no Wh) =================
    #pragma unroll
    for (int nt = 0; nt < 4; ++nt) {
        const float mb = msg_b0[nt * 16 + m];
        #pragma unroll
        for (int rt = 0; rt < 2; ++rt)
            #pragma unroll
            for (int r = 0; r < 4; ++r)
                zv[rt][nt][r] = xv[rt][nt][r] + mb;
    }
    write_cd(sb, zv, lane);
    read_af(sb, lane, az);

    gate_mm<false>(wsQ, T_WX0, 0, 0, az, az, lstm_b0, lane, tg);   // i
    FORALL { si[rt][nt][r] = fsig(tg[rt][nt][r]); }
    gate_mm<false>(wsQ, T_WX0, 0, 2, az, az, lstm_b0, lane, tg);   // g
    FORALL { cv[rt][nt][r] = si[rt][nt][r] * ftanh(tg[rt][nt][r]); }
    gate_mm<false>(wsQ, T_WX0, 0, 3, az, az, lstm_b0, lane, tg);   // o
    FORALL { hv[rt][nt][r] = ftanh(fsig(tg[rt][nt][r]) * ftanh(cv[rt][nt][r]) + zv[rt][nt][r]); }

    // ================= hop 1 (full) =================
    {
        float cm[2][4][4];
        #pragma unroll
        for (int nt = 0; nt < 4; ++nt) {
            float p = 0.f;
            #pragma unroll
            for (int rt = 0; rt < 2; ++rt)
                #pragma unroll
                for (int r = 0; r < 4; ++r) p += hv[rt][nt][r];
            p += __shfl_xor(p, 16);
            p += __shfl_xor(p, 32);
            #pragma unroll
            for (int rt = 0; rt < 2; ++rt)
                #pragma unroll
                for (int r = 0; r < 4; ++r)
                    cm[rt][nt][r] = (p - hv[rt][nt][r]) * (1.0f / 31.0f);
        }
        write_cd(sb, cm, lane);
        read_af(sb, lane, az);      // comm fragments
    }
    // msg = comm @ msg_W1 + msg_b1 ; z = x + msg
    #pragma unroll
    for (int nt = 0; nt < 4; ++nt) {
        f32x4 a0 = {0.f, 0.f, 0.f, 0.f};
        f32x4 a1 = {0.f, 0.f, 0.f, 0.f};
        #pragma unroll
        for (int kt = 0; kt < 2; ++kt) {
            FragU bw; bw.q = wsQ[(size_t)(T_MSG1 + nt * 2 + kt) * 64 + lane];
            a0 = __builtin_amdgcn_mfma_f32_16x16x32_bf16(az[0][kt].v, bw.v, a0, 0, 0, 0);
            a1 = __builtin_amdgcn_mfma_f32_16x16x32_bf16(az[1][kt].v, bw.v, a1, 0, 0, 0);
        }
        const float mb = msg_b1[nt * 16 + m];
        #pragma unroll
        for (int r = 0; r < 4; ++r) {
            zv[0][nt][r] = xv[0][nt][r] + a0[r] + mb;
            zv[1][nt][r] = xv[1][nt][r] + a1[r] + mb;
        }
    }
    write_cd(sb, zv, lane);
    read_af(sb, lane, az);          // z fragments
    write_cd(sb, hv, lane);
    read_af(sb, lane, ah);          // h fragments

    gate_mm<true>(wsQ, T_WX1, T_WH1, 1, az, ah, lstm_b1, lane, tg);   // f
    FORALL { cv[rt][nt][r] = fsig(tg[rt][nt][r]) * cv[rt][nt][r]; }
    gate_mm<true>(wsQ, T_WX1, T_WH1, 0, az, ah, lstm_b1, lane, tg);   // i
    FORALL { si[rt][nt][r] = fsig(tg[rt][nt][r]); }
    gate_mm<true>(wsQ, T_WX1, T_WH1, 2, az, ah, lstm_b1, lane, tg);   // g
    FORALL { cv[rt][nt][r] = fmaf(si[rt][nt][r], ftanh(tg[rt][nt][r]), cv[rt][nt][r]); }
    gate_mm<true>(wsQ, T_WX1, T_WH1, 3, az, ah, lstm_b1, lane, tg);   // o
    FORALL { hv[rt][nt][r] = ftanh(fsig(tg[rt][nt][r]) * ftanh(cv[rt][nt][r]) + zv[rt][nt][r]); }

    // ================= heads =================
    write_cd(sb, hv, lane);
    read_af(sb, lane, ah);          // h fragments for logits
    {
        f32x4 l0 = {0.f, 0.f, 0.f, 0.f};
        f32x4 l1 = {0.f, 0.f, 0.f, 0.f};
        #pragma unroll
        for (int kt = 0; kt < 2; ++kt) {
            FragU bw; bw.q = wsQ[(size_t)(T_ACT + kt) * 64 + lane];
            l0 = __builtin_amdgcn_mfma_f32_16x16x32_bf16(ah[0][kt].v, bw.v, l0, 0, 0, 0);
            l1 = __builtin_amdgcn_mfma_f32_16x16x32_bf16(ah[1][kt].v, bw.v, l1, 0, 0, 0);
        }
        const float ab = act_b[m];
        #pragma unroll
        for (int r = 0; r < 4; ++r) {
            out[(size_t)(b * Nn +      g * 4 + r) * An + m] = l0[r] + ab;
            out[(size_t)(b * Nn + 16 + g * 4 + r) * An + m] = l1[r] + ab;
        }
    }
    // values
    {
        float vwv[4];
        #pragma unroll
        for (int nt = 0; nt < 4; ++nt) vwv[nt] = val_W[nt * 16 + m];
        const float vb = val_b[0];
        #pragma unroll
        for (int rt = 0; rt < 2; ++rt) {
            float p0 = 0.f, p1 = 0.f, p2 = 0.f, p3 = 0.f;
            #pragma unroll
            for (int nt = 0; nt < 4; ++nt) {
                p0 = fmaf(hv[rt][nt][0], vwv[nt], p0);
                p1 = fmaf(hv[rt][nt][1], vwv[nt], p1);
                p2 = fmaf(hv[rt][nt][2], vwv[nt], p2);
                p3 = fmaf(hv[rt][nt][3], vwv[nt], p3);
            }
            #pragma unroll
            for (int s = 1; s < 16; s <<= 1) {
                p0 += __shfl_xor(p0, s);
                p1 += __shfl_xor(p1, s);
                p2 += __shfl_xor(p2, s);
                p3 += __shfl_xor(p3, s);
            }
            float sel = (m == 0) ? p0 : (m == 1) ? p1 : (m == 2) ? p2 : p3;
            if (m < 4)
                out[VOFF + (size_t)b * Nn + rt * 16 + g * 4 + m] = sel + vb;
        }
    }
    // h_round, c_round
    {
        float* oh = out + HOFF;
        float* oc = out + COFF;
        FORALL {
            const size_t row = (size_t)b * Nn + rt * 16 + g * 4 + r;
            oh[row * Hn + nt * 16 + m] = hv[rt][nt][r];
            oc[row * Hn + nt * 16 + m] = cv[rt][nt][r];
        }
    }
}

// ---------------- launch ----------------
extern "C" void kernel_launch(void* const* d_in, const int* in_sizes, int n_in,
                              void* d_out, int out_size, void* d_ws, size_t ws_size,
                              hipStream_t stream) {
    const float* obs      = (const float*)d_in[0];
    const float* enc_W    = (const float*)d_in[1];
    const float* enc_b    = (const float*)d_in[2];
    const float* msg_W0   = (const float*)d_in[3];
    const float* msg_b0   = (const float*)d_in[4];
    const float* msg_W1   = (const float*)d_in[5];
    const float* msg_b1   = (const float*)d_in[6];
    const float* lstm_Wx0 = (const float*)d_in[7];
    const float* lstm_Wh0 = (const float*)d_in[8];
    const float* lstm_b0  = (const float*)d_in[9];
    const float* lstm_Wx1 = (const float*)d_in[10];
    const float* lstm_Wh1 = (const float*)d_in[11];
    const float* lstm_b1  = (const float*)d_in[12];
    const float* act_W    = (const float*)d_in[13];
    const float* act_b    = (const float*)d_in[14];
    const float* val_W    = (const float*)d_in[15];
    const float* val_b    = (const float*)d_in[16];

    uint4* ws = (uint4*)d_ws;

    commnet_prep<<<(T_TOT * 64 + 255) / 256, 256, 0, stream>>>(
        enc_W, msg_W0, msg_W1, lstm_Wx0, lstm_Wh0, lstm_Wx1, lstm_Wh1, act_W, ws);

    commnet_main<<<Bn / 4, 256, 0, stream>>>(
        obs, ws, enc_b, msg_b0, msg_b1, lstm_b0, lstm_b1,
        act_b, val_W, val_b, (float*)d_out);
}